// Round 1
// baseline (1577.166 us; speedup 1.0000x reference)
//
#include <hip/hip_runtime.h>
#include <math.h>

#define IMGSZ 256
#define HW (IMGSZ * IMGSZ)
#define EPSF 1e-8f
#define BIGF 1e10f

// ---------------- Kernel A: vertex transform + zero vn accumulator ----------
__global__ void k_transform(const float* __restrict__ verts,
                            const float* __restrict__ tm,
                            const float* __restrict__ focal,
                            float* __restrict__ xn, float* __restrict__ yn,
                            float* __restrict__ zv, float* __restrict__ vnacc,
                            int V) {
#pragma clang fp contract(off)
    int i = blockIdx.x * blockDim.x + threadIdx.x;
    if (i >= V) return;
    float vx = verts[i * 3 + 0], vy = verts[i * 3 + 1], vz = verts[i * 3 + 2];
    // v_view[j] = sum_i v[i]*R[i][j] + T[j];  R[i][j]=tm[i*4+j], T[j]=tm[j*4+3]
    float xv = ((vx * tm[0] + vy * tm[4]) + vz * tm[8]) + tm[3];
    float yv = ((vx * tm[1] + vy * tm[5]) + vz * tm[9]) + tm[7];
    float zw = ((vx * tm[2] + vy * tm[6]) + vz * tm[10]) + tm[11];
    float zc = fmaxf(zw, EPSF);
    float fx = 2.0f * focal[0] / (float)IMGSZ;
    float fy = 2.0f * focal[1] / (float)IMGSZ;
    xn[i] = fx * xv / zc;
    yn[i] = fy * yv / zc;
    zv[i] = zw;
    vnacc[i * 3 + 0] = 0.0f;
    vnacc[i * 3 + 1] = 0.0f;
    vnacc[i * 3 + 2] = 0.0f;
}

// ---------------- Kernel B: per-face setup + normal accumulation ------------
__global__ void k_facesetup(const int* __restrict__ faces,
                            const float* __restrict__ verts,
                            const float* __restrict__ xn,
                            const float* __restrict__ yn,
                            const float* __restrict__ zv,
                            float4* __restrict__ fd,
                            float* __restrict__ vnacc, int F) {
#pragma clang fp contract(off)
    int f = blockIdx.x * blockDim.x + threadIdx.x;
    if (f >= F) return;
    int i0 = faces[f * 3 + 0], i1 = faces[f * 3 + 1], i2 = faces[f * 3 + 2];
    float x0 = xn[i0], x1 = xn[i1], x2 = xn[i2];
    float y0 = yn[i0], y1 = yn[i1], y2 = yn[i2];
    float z0 = zv[i0], z1 = zv[i1], z2 = zv[i2];
    float area = (x1 - x0) * (y2 - y0) - (x2 - x0) * (y1 - y0);
    bool zok = (z0 > EPSF) && (z1 > EPSF) && (z2 > EPSF);
    float areaStore = zok ? area : 0.0f;  // area==0 => culled (|area|<=EPS)
    fd[f * 3 + 0] = make_float4(x0, y0, x1, y1);
    fd[f * 3 + 1] = make_float4(x2, y2, areaStore, __int_as_float(f));
    fd[f * 3 + 2] = make_float4(fmaxf(z0, EPSF), fmaxf(z1, EPSF), fmaxf(z2, EPSF), 0.0f);
    // face normal (object space), scatter-add to vertex normals
    float a0 = verts[i0 * 3 + 0], a1 = verts[i0 * 3 + 1], a2 = verts[i0 * 3 + 2];
    float b0 = verts[i1 * 3 + 0], b1 = verts[i1 * 3 + 1], b2 = verts[i1 * 3 + 2];
    float c0 = verts[i2 * 3 + 0], c1 = verts[i2 * 3 + 1], c2 = verts[i2 * 3 + 2];
    float e1x = b0 - a0, e1y = b1 - a1, e1z = b2 - a2;
    float e2x = c0 - a0, e2y = c1 - a1, e2z = c2 - a2;
    float nx = e1y * e2z - e1z * e2y;
    float ny = e1z * e2x - e1x * e2z;
    float nz = e1x * e2y - e1y * e2x;
    atomicAdd(&vnacc[i0 * 3 + 0], nx);
    atomicAdd(&vnacc[i0 * 3 + 1], ny);
    atomicAdd(&vnacc[i0 * 3 + 2], nz);
    atomicAdd(&vnacc[i1 * 3 + 0], nx);
    atomicAdd(&vnacc[i1 * 3 + 1], ny);
    atomicAdd(&vnacc[i1 * 3 + 2], nz);
    atomicAdd(&vnacc[i2 * 3 + 0], nx);
    atomicAdd(&vnacc[i2 * 3 + 1], ny);
    atomicAdd(&vnacc[i2 * 3 + 2], nz);
}

// ---------------- Kernel C: normalize vertex normals ------------------------
__global__ void k_vnorm(float* __restrict__ vn, int V) {
#pragma clang fp contract(off)
    int i = blockIdx.x * blockDim.x + threadIdx.x;
    if (i >= V) return;
    float x = vn[i * 3 + 0], y = vn[i * 3 + 1], z = vn[i * 3 + 2];
    float n = sqrtf((x * x + y * y) + z * z) + EPSF;
    vn[i * 3 + 0] = x / n;
    vn[i * 3 + 1] = y / n;
    vn[i * 3 + 2] = z / n;
}

// ---------------- Kernel D: tiled raster + shade ----------------------------
__launch_bounds__(256)
__global__ void k_raster(const float4* __restrict__ fd, int F,
                         const int* __restrict__ faces,
                         const float* __restrict__ verts,
                         const float* __restrict__ vn,
                         const float* __restrict__ tm,
                         float* __restrict__ out) {
#pragma clang fp contract(off)
    __shared__ float4 sfd[256 * 3];
    __shared__ int scnt[4];

    int t = threadIdx.x;
    int lane = t & 63, wid = t >> 6;
    int tileX = blockIdx.x & 15, tileY = blockIdx.x >> 4;
    int col = tileX * 16 + (t & 15);
    int row = tileY * 16 + (t >> 4);
    float P = 1.0f - 2.0f * ((float)col + 0.5f) / (float)IMGSZ;
    float Q = 1.0f - 2.0f * ((float)row + 0.5f) / (float)IMGSZ;
    // NDC x decreases with col; y decreases with row
    float txmax = 1.0f - 2.0f * ((float)(tileX * 16) + 0.5f) / (float)IMGSZ;
    float txmin = 1.0f - 2.0f * ((float)(tileX * 16 + 15) + 0.5f) / (float)IMGSZ;
    float tymax = 1.0f - 2.0f * ((float)(tileY * 16) + 0.5f) / (float)IMGSZ;
    float tymin = 1.0f - 2.0f * ((float)(tileY * 16 + 15) + 0.5f) / (float)IMGSZ;
    const float M = 1e-4f;  // conservative cull margin

    float best = BIGF;
    int bestf = 0;
    float bp0 = 0.0f, bp1 = 0.0f;

    for (int base = 0; base < F; base += 256) {
        int f = base + t;
        bool pass = false;
        float4 A, B, C;
        if (f < F) {
            A = fd[f * 3 + 0];
            B = fd[f * 3 + 1];
            C = fd[f * 3 + 2];
            float area = B.z;
            if (fabsf(area) > EPSF) {
                float mnx = fminf(fminf(A.x, A.z), B.x);
                float mxx = fmaxf(fmaxf(A.x, A.z), B.x);
                float mny = fminf(fminf(A.y, A.w), B.y);
                float mxy = fmaxf(fmaxf(A.y, A.w), B.y);
                pass = (mnx <= txmax + M) && (mxx >= txmin - M) &&
                       (mny <= tymax + M) && (mxy >= tymin - M);
            }
        }
        unsigned long long m = __ballot(pass);
        if (lane == 0) scnt[wid] = __popcll(m);
        __syncthreads();
        int off = 0;
#pragma unroll
        for (int w = 0; w < 4; ++w)
            if (w < wid) off += scnt[w];
        int total = scnt[0] + scnt[1] + scnt[2] + scnt[3];
        if (pass) {
            int rank = __popcll(m & ((1ull << lane) - 1ull));
            int s = off + rank;  // order-preserving compaction
            sfd[s * 3 + 0] = A;
            sfd[s * 3 + 1] = B;
            sfd[s * 3 + 2] = C;
        }
        __syncthreads();
        for (int s = 0; s < total; ++s) {
            float4 a = sfd[s * 3 + 0], b = sfd[s * 3 + 1], c = sfd[s * 3 + 2];
            float e0x = a.x - P, e0y = a.y - Q;
            float e1x = a.z - P, e1y = a.w - Q;
            float e2x = b.x - P, e2y = b.y - Q;
            float w0 = e1x * e2y - e2x * e1y;
            float w1 = e2x * e0y - e0x * e2y;
            float area = b.z;
            float w2 = (area - w0) - w1;
            // sign-equivalent to (w/area >= 0) for |area|>EPS, incl. +/-0
            bool inside = (area > 0.0f) ? (w0 >= 0.0f && w1 >= 0.0f && w2 >= 0.0f)
                                        : (w0 <= 0.0f && w1 <= 0.0f && w2 <= 0.0f);
            if (inside) {
                float b0v = w0 / area, b1v = w1 / area, b2v = w2 / area;
                float t0 = b0v / c.x, t1 = b1v / c.y, t2v = b2v / c.z;
                float invz = (t0 + t1) + t2v;
                float zpix = 1.0f / fmaxf(invz, EPSF);
                if (zpix < best) {
                    best = zpix;
                    bestf = __float_as_int(b.w);
                    bp0 = t0 * zpix;
                    bp1 = t1 * zpix;
                }
            }
        }
        __syncthreads();
    }

    // ------- shading -------
    int pix = row * IMGSZ + col;
    float val = 0.0f, alpha = 0.0f;
    if (best < 0.5f * BIGF) {
        int i0 = faces[bestf * 3 + 0], i1 = faces[bestf * 3 + 1], i2 = faces[bestf * 3 + 2];
        float b0v = bp0, b1v = bp1, b2v = (1.0f - bp0) - bp1;
        float Pwx = (b0v * verts[i0 * 3 + 0] + b1v * verts[i1 * 3 + 0]) + b2v * verts[i2 * 3 + 0];
        float Pwy = (b0v * verts[i0 * 3 + 1] + b1v * verts[i1 * 3 + 1]) + b2v * verts[i2 * 3 + 1];
        float Pwz = (b0v * verts[i0 * 3 + 2] + b1v * verts[i1 * 3 + 2]) + b2v * verts[i2 * 3 + 2];
        float Nx = (b0v * vn[i0 * 3 + 0] + b1v * vn[i1 * 3 + 0]) + b2v * vn[i2 * 3 + 0];
        float Ny = (b0v * vn[i0 * 3 + 1] + b1v * vn[i1 * 3 + 1]) + b2v * vn[i2 * 3 + 1];
        float Nz = (b0v * vn[i0 * 3 + 2] + b1v * vn[i1 * 3 + 2]) + b2v * vn[i2 * 3 + 2];
        float nn = sqrtf((Nx * Nx + Ny * Ny) + Nz * Nz) + EPSF;
        Nx /= nn; Ny /= nn; Nz /= nn;
        // cam = -T R^T : cam[k] = -(T0*R[k][0] + T1*R[k][1] + T2*R[k][2])
        float T0 = tm[3], T1 = tm[7], T2 = tm[11];
        float camx = -((T0 * tm[0] + T1 * tm[1]) + T2 * tm[2]);
        float camy = -((T0 * tm[4] + T1 * tm[5]) + T2 * tm[6]);
        float camz = -((T0 * tm[8] + T1 * tm[9]) + T2 * tm[10]);
        float Ldx = 0.0f - Pwx, Ldy = 0.0f - Pwy, Ldz = 3.0f - Pwz;
        float ln = sqrtf((Ldx * Ldx + Ldy * Ldy) + Ldz * Ldz) + EPSF;
        Ldx /= ln; Ldy /= ln; Ldz /= ln;
        float Vx = camx - Pwx, Vy = camy - Pwy, Vz = camz - Pwz;
        float vv = sqrtf((Vx * Vx + Vy * Vy) + Vz * Vz) + EPSF;
        Vx /= vv; Vy /= vv; Vz /= vv;
        float dt = (Nx * Ldx + Ny * Ldy) + Nz * Ldz;
        float ndl = fmaxf(dt, 0.0f);
        float twodt = 2.0f * dt;
        float rx = -Ldx + twodt * Nx;
        float ry = -Ldy + twodt * Ny;
        float rz = -Ldz + twodt * Nz;
        float sdot = (rx * Vx + ry * Vy) + rz * Vz;
        float sb = fmaxf(sdot, 0.0f);
        float s2 = sb * sb, s4 = s2 * s2, s8 = s4 * s4, s16 = s8 * s8, s32 = s16 * s16;
        float spec = s32 * s32;  // sb^64
        float shade = (0.5f + 0.3f * ndl) + 0.2f * spec;
        val = shade * 255.0f;
        alpha = 1.0f;
    }
    out[0 * HW + pix] = val;
    out[1 * HW + pix] = val;
    out[2 * HW + pix] = val;
    out[3 * HW + pix] = alpha;
}

// ---------------- launcher --------------------------------------------------
extern "C" void kernel_launch(void* const* d_in, const int* in_sizes, int n_in,
                              void* d_out, int out_size, void* d_ws, size_t ws_size,
                              hipStream_t stream) {
    const float* verts = (const float*)d_in[0];
    const float* tm = (const float*)d_in[1];
    const float* focal = (const float*)d_in[2];
    const int* faces = (const int*)d_in[3];
    int V = in_sizes[0] / 3;  // B=1
    int F = in_sizes[3] / 3;

    float* ws = (float*)d_ws;
    float* xn = ws;
    float* yn = ws + V;
    float* zv = ws + 2 * (size_t)V;
    float* vn = ws + 3 * (size_t)V;
    size_t fdOff = (6 * (size_t)V + 3) & ~(size_t)3;  // 16B-align the float4 array
    float4* fd = (float4*)(ws + fdOff);
    float* out = (float*)d_out;

    int vb = (V + 255) / 256;
    int fb = (F + 255) / 256;
    k_transform<<<vb, 256, 0, stream>>>(verts, tm, focal, xn, yn, zv, vn, V);
    k_facesetup<<<fb, 256, 0, stream>>>(faces, verts, xn, yn, zv, fd, vn, F);
    k_vnorm<<<vb, 256, 0, stream>>>(vn, V);
    k_raster<<<256, 256, 0, stream>>>(fd, F, faces, verts, vn, tm, out);
}

// Round 2
// 771.373 us; speedup vs baseline: 2.0446x; 2.0446x over previous
//
#include <hip/hip_runtime.h>
#include <math.h>

#define IMGSZ 256
#define HW (IMGSZ * IMGSZ)
#define EPSF 1e-8f
#define BIGF 1e10f
#define NSLICE 8

// ---------------- Kernel A: vertex transform + zero vn accumulator ----------
__global__ void k_transform(const float* __restrict__ verts,
                            const float* __restrict__ tm,
                            const float* __restrict__ focal,
                            float* __restrict__ xn, float* __restrict__ yn,
                            float* __restrict__ zv, float* __restrict__ vnacc,
                            int V) {
#pragma clang fp contract(off)
    int i = blockIdx.x * blockDim.x + threadIdx.x;
    if (i >= V) return;
    float vx = verts[i * 3 + 0], vy = verts[i * 3 + 1], vz = verts[i * 3 + 2];
    float xv = ((vx * tm[0] + vy * tm[4]) + vz * tm[8]) + tm[3];
    float yv = ((vx * tm[1] + vy * tm[5]) + vz * tm[9]) + tm[7];
    float zw = ((vx * tm[2] + vy * tm[6]) + vz * tm[10]) + tm[11];
    float zc = fmaxf(zw, EPSF);
    float fx = 2.0f * focal[0] / (float)IMGSZ;
    float fy = 2.0f * focal[1] / (float)IMGSZ;
    xn[i] = fx * xv / zc;
    yn[i] = fy * yv / zc;
    zv[i] = zw;
    vnacc[i * 3 + 0] = 0.0f;
    vnacc[i * 3 + 1] = 0.0f;
    vnacc[i * 3 + 2] = 0.0f;
}

// ---------------- Kernel B: per-face setup + normal accumulation ------------
__global__ void k_facesetup(const int* __restrict__ faces,
                            const float* __restrict__ verts,
                            const float* __restrict__ xn,
                            const float* __restrict__ yn,
                            const float* __restrict__ zv,
                            float4* __restrict__ fd,
                            float* __restrict__ vnacc, int F) {
#pragma clang fp contract(off)
    int f = blockIdx.x * blockDim.x + threadIdx.x;
    if (f >= F) return;
    int i0 = faces[f * 3 + 0], i1 = faces[f * 3 + 1], i2 = faces[f * 3 + 2];
    float x0 = xn[i0], x1 = xn[i1], x2 = xn[i2];
    float y0 = yn[i0], y1 = yn[i1], y2 = yn[i2];
    float z0 = zv[i0], z1 = zv[i1], z2 = zv[i2];
    float area = (x1 - x0) * (y2 - y0) - (x2 - x0) * (y1 - y0);
    bool zok = (z0 > EPSF) && (z1 > EPSF) && (z2 > EPSF);
    float areaStore = zok ? area : 0.0f;  // area==0 => culled (|area|<=EPS)
    fd[f * 3 + 0] = make_float4(x0, y0, x1, y1);
    fd[f * 3 + 1] = make_float4(x2, y2, areaStore, __int_as_float(f));
    fd[f * 3 + 2] = make_float4(fmaxf(z0, EPSF), fmaxf(z1, EPSF), fmaxf(z2, EPSF), 0.0f);
    float a0 = verts[i0 * 3 + 0], a1 = verts[i0 * 3 + 1], a2 = verts[i0 * 3 + 2];
    float b0 = verts[i1 * 3 + 0], b1 = verts[i1 * 3 + 1], b2 = verts[i1 * 3 + 2];
    float c0 = verts[i2 * 3 + 0], c1 = verts[i2 * 3 + 1], c2 = verts[i2 * 3 + 2];
    float e1x = b0 - a0, e1y = b1 - a1, e1z = b2 - a2;
    float e2x = c0 - a0, e2y = c1 - a1, e2z = c2 - a2;
    float nx = e1y * e2z - e1z * e2y;
    float ny = e1z * e2x - e1x * e2z;
    float nz = e1x * e2y - e1y * e2x;
    atomicAdd(&vnacc[i0 * 3 + 0], nx);
    atomicAdd(&vnacc[i0 * 3 + 1], ny);
    atomicAdd(&vnacc[i0 * 3 + 2], nz);
    atomicAdd(&vnacc[i1 * 3 + 0], nx);
    atomicAdd(&vnacc[i1 * 3 + 1], ny);
    atomicAdd(&vnacc[i1 * 3 + 2], nz);
    atomicAdd(&vnacc[i2 * 3 + 0], nx);
    atomicAdd(&vnacc[i2 * 3 + 1], ny);
    atomicAdd(&vnacc[i2 * 3 + 2], nz);
}

// ---------------- Kernel C: normalize vertex normals ------------------------
__global__ void k_vnorm(float* __restrict__ vn, int V) {
#pragma clang fp contract(off)
    int i = blockIdx.x * blockDim.x + threadIdx.x;
    if (i >= V) return;
    float x = vn[i * 3 + 0], y = vn[i * 3 + 1], z = vn[i * 3 + 2];
    float n = sqrtf((x * x + y * y) + z * z) + EPSF;
    vn[i * 3 + 0] = x / n;
    vn[i * 3 + 1] = y / n;
    vn[i * 3 + 2] = z / n;
}

// ---------------- Kernel Z: init packed z-buffer ----------------------------
__global__ void k_zinit(unsigned long long* __restrict__ zb) {
    zb[blockIdx.x * 256 + threadIdx.x] = 0xFFFFFFFFFFFFFFFFull;
}

// ---------------- Kernel D: tiled raster (face-sliced, atomic merge) --------
__launch_bounds__(256)
__global__ void k_raster(const float4* __restrict__ fd, int F, int sliceLen,
                         unsigned long long* __restrict__ zb) {
#pragma clang fp contract(off)
    __shared__ float4 sfd[256 * 3];
    __shared__ int scnt[4];

    int t = threadIdx.x;
    int lane = t & 63, wid = t >> 6;
    int tile = blockIdx.x & 255;
    int slice = blockIdx.x >> 8;
    int tileX = tile & 15, tileY = tile >> 4;
    int col = tileX * 16 + (t & 15);
    int row = tileY * 16 + (t >> 4);
    float P = 1.0f - 2.0f * ((float)col + 0.5f) / (float)IMGSZ;
    float Q = 1.0f - 2.0f * ((float)row + 0.5f) / (float)IMGSZ;
    float txmax = 1.0f - 2.0f * ((float)(tileX * 16) + 0.5f) / (float)IMGSZ;
    float txmin = 1.0f - 2.0f * ((float)(tileX * 16 + 15) + 0.5f) / (float)IMGSZ;
    float tymax = 1.0f - 2.0f * ((float)(tileY * 16) + 0.5f) / (float)IMGSZ;
    float tymin = 1.0f - 2.0f * ((float)(tileY * 16 + 15) + 0.5f) / (float)IMGSZ;
    const float M = 1e-4f;

    int fbeg = slice * sliceLen;
    int fend = fbeg + sliceLen;
    if (fend > F) fend = F;

    unsigned long long bestpk = 0xFFFFFFFFFFFFFFFFull;

    for (int base = fbeg; base < fend; base += 256) {
        int f = base + t;
        bool pass = false;
        float4 A, B, C;
        if (f < fend) {
            A = fd[f * 3 + 0];
            B = fd[f * 3 + 1];
            C = fd[f * 3 + 2];
            float area = B.z;
            if (fabsf(area) > EPSF) {
                float mnx = fminf(fminf(A.x, A.z), B.x);
                float mxx = fmaxf(fmaxf(A.x, A.z), B.x);
                float mny = fminf(fminf(A.y, A.w), B.y);
                float mxy = fmaxf(fmaxf(A.y, A.w), B.y);
                pass = (mnx <= txmax + M) && (mxx >= txmin - M) &&
                       (mny <= tymax + M) && (mxy >= tymin - M);
            }
        }
        unsigned long long m = __ballot(pass);
        if (lane == 0) scnt[wid] = __popcll(m);
        __syncthreads();
        int off = 0;
#pragma unroll
        for (int w = 0; w < 4; ++w)
            if (w < wid) off += scnt[w];
        int total = scnt[0] + scnt[1] + scnt[2] + scnt[3];
        if (pass) {
            int rank = __popcll(m & ((1ull << lane) - 1ull));
            int s = off + rank;  // order-preserving compaction
            sfd[s * 3 + 0] = A;
            sfd[s * 3 + 1] = B;
            sfd[s * 3 + 2] = C;
        }
        __syncthreads();
        for (int s = 0; s < total; ++s) {
            float4 a = sfd[s * 3 + 0], b = sfd[s * 3 + 1], c = sfd[s * 3 + 2];
            float e0x = a.x - P, e0y = a.y - Q;
            float e1x = a.z - P, e1y = a.w - Q;
            float e2x = b.x - P, e2y = b.y - Q;
            float w0 = e1x * e2y - e2x * e1y;
            float w1 = e2x * e0y - e0x * e2y;
            float area = b.z;
            float w2 = (area - w0) - w1;
            bool inside = (area > 0.0f) ? (w0 >= 0.0f && w1 >= 0.0f && w2 >= 0.0f)
                                        : (w0 <= 0.0f && w1 <= 0.0f && w2 <= 0.0f);
            if (inside) {
                float b0v = w0 / area, b1v = w1 / area, b2v = w2 / area;
                float t0 = b0v / c.x, t1 = b1v / c.y, t2v = b2v / c.z;
                float invz = (t0 + t1) + t2v;
                float zpix = 1.0f / fmaxf(invz, EPSF);
                // lexicographic (depth, face_id) — matches reference tie-break
                unsigned long long pk =
                    ((unsigned long long)(unsigned int)__float_as_int(zpix) << 32) |
                    (unsigned int)__float_as_int(b.w);
                if (pk < bestpk) bestpk = pk;
            }
        }
        __syncthreads();
    }

    if (bestpk != 0xFFFFFFFFFFFFFFFFull) {
        int pix = row * IMGSZ + col;
        atomicMin(&zb[pix], bestpk);
    }
}

// ---------------- Kernel E: shade winners -----------------------------------
__launch_bounds__(256)
__global__ void k_shade(const unsigned long long* __restrict__ zb,
                        const float4* __restrict__ fd,
                        const int* __restrict__ faces,
                        const float* __restrict__ verts,
                        const float* __restrict__ vn,
                        const float* __restrict__ tm,
                        float* __restrict__ out) {
#pragma clang fp contract(off)
    int pix = blockIdx.x * 256 + threadIdx.x;
    unsigned long long pk = zb[pix];
    float val = 0.0f, alpha = 0.0f;
    if (pk != 0xFFFFFFFFFFFFFFFFull) {
        int bestf = (int)(unsigned int)(pk & 0xFFFFFFFFull);
        int col = pix & (IMGSZ - 1), row = pix >> 8;
        float P = 1.0f - 2.0f * ((float)col + 0.5f) / (float)IMGSZ;
        float Q = 1.0f - 2.0f * ((float)row + 0.5f) / (float)IMGSZ;
        float4 a = fd[bestf * 3 + 0], b = fd[bestf * 3 + 1], c = fd[bestf * 3 + 2];
        float e0x = a.x - P, e0y = a.y - Q;
        float e1x = a.z - P, e1y = a.w - Q;
        float e2x = b.x - P, e2y = b.y - Q;
        float w0 = e1x * e2y - e2x * e1y;
        float w1 = e2x * e0y - e0x * e2y;
        float area = b.z;
        float t0 = (w0 / area) / c.x, t1 = (w1 / area) / c.y;
        float t2v = (((area - w0) - w1) / area) / c.z;
        float invz = (t0 + t1) + t2v;
        float zpix = 1.0f / fmaxf(invz, EPSF);
        float bp0 = t0 * zpix, bp1 = t1 * zpix;

        int i0 = faces[bestf * 3 + 0], i1 = faces[bestf * 3 + 1], i2 = faces[bestf * 3 + 2];
        float b0v = bp0, b1v = bp1, b2v = (1.0f - bp0) - bp1;
        float Pwx = (b0v * verts[i0 * 3 + 0] + b1v * verts[i1 * 3 + 0]) + b2v * verts[i2 * 3 + 0];
        float Pwy = (b0v * verts[i0 * 3 + 1] + b1v * verts[i1 * 3 + 1]) + b2v * verts[i2 * 3 + 1];
        float Pwz = (b0v * verts[i0 * 3 + 2] + b1v * verts[i1 * 3 + 2]) + b2v * verts[i2 * 3 + 2];
        float Nx = (b0v * vn[i0 * 3 + 0] + b1v * vn[i1 * 3 + 0]) + b2v * vn[i2 * 3 + 0];
        float Ny = (b0v * vn[i0 * 3 + 1] + b1v * vn[i1 * 3 + 1]) + b2v * vn[i2 * 3 + 1];
        float Nz = (b0v * vn[i0 * 3 + 2] + b1v * vn[i1 * 3 + 2]) + b2v * vn[i2 * 3 + 2];
        float nn = sqrtf((Nx * Nx + Ny * Ny) + Nz * Nz) + EPSF;
        Nx /= nn; Ny /= nn; Nz /= nn;
        float T0 = tm[3], T1 = tm[7], T2 = tm[11];
        float camx = -((T0 * tm[0] + T1 * tm[1]) + T2 * tm[2]);
        float camy = -((T0 * tm[4] + T1 * tm[5]) + T2 * tm[6]);
        float camz = -((T0 * tm[8] + T1 * tm[9]) + T2 * tm[10]);
        float Ldx = 0.0f - Pwx, Ldy = 0.0f - Pwy, Ldz = 3.0f - Pwz;
        float ln = sqrtf((Ldx * Ldx + Ldy * Ldy) + Ldz * Ldz) + EPSF;
        Ldx /= ln; Ldy /= ln; Ldz /= ln;
        float Vx = camx - Pwx, Vy = camy - Pwy, Vz = camz - Pwz;
        float vv = sqrtf((Vx * Vx + Vy * Vy) + Vz * Vz) + EPSF;
        Vx /= vv; Vy /= vv; Vz /= vv;
        float dt = (Nx * Ldx + Ny * Ldy) + Nz * Ldz;
        float ndl = fmaxf(dt, 0.0f);
        float twodt = 2.0f * dt;
        float rx = -Ldx + twodt * Nx;
        float ry = -Ldy + twodt * Ny;
        float rz = -Ldz + twodt * Nz;
        float sdot = (rx * Vx + ry * Vy) + rz * Vz;
        float sb = fmaxf(sdot, 0.0f);
        float s2 = sb * sb, s4 = s2 * s2, s8 = s4 * s4, s16 = s8 * s8, s32 = s16 * s16;
        float spec = s32 * s32;  // sb^64
        float shade = (0.5f + 0.3f * ndl) + 0.2f * spec;
        val = shade * 255.0f;
        alpha = 1.0f;
    }
    out[0 * HW + pix] = val;
    out[1 * HW + pix] = val;
    out[2 * HW + pix] = val;
    out[3 * HW + pix] = alpha;
}

// ---------------- launcher --------------------------------------------------
extern "C" void kernel_launch(void* const* d_in, const int* in_sizes, int n_in,
                              void* d_out, int out_size, void* d_ws, size_t ws_size,
                              hipStream_t stream) {
    const float* verts = (const float*)d_in[0];
    const float* tm = (const float*)d_in[1];
    const float* focal = (const float*)d_in[2];
    const int* faces = (const int*)d_in[3];
    int V = in_sizes[0] / 3;  // B=1
    int F = in_sizes[3] / 3;

    // ws layout: [zbuf64: HW u64][xn,yn,zv: 3V][vn: 3V][fd: 12F floats]
    unsigned long long* zb = (unsigned long long*)d_ws;
    float* ws = (float*)d_ws + 2 * (size_t)HW;
    float* xn = ws;
    float* yn = ws + V;
    float* zv = ws + 2 * (size_t)V;
    float* vn = ws + 3 * (size_t)V;
    size_t fdOff = (6 * (size_t)V + 3) & ~(size_t)3;  // 16B-align
    float4* fd = (float4*)(ws + fdOff);
    float* out = (float*)d_out;

    int vb = (V + 255) / 256;
    int fb = (F + 255) / 256;
    int sliceLen = (F + NSLICE - 1) / NSLICE;
    k_transform<<<vb, 256, 0, stream>>>(verts, tm, focal, xn, yn, zv, vn, V);
    k_zinit<<<HW / 256, 256, 0, stream>>>(zb);
    k_facesetup<<<fb, 256, 0, stream>>>(faces, verts, xn, yn, zv, fd, vn, F);
    k_vnorm<<<vb, 256, 0, stream>>>(vn, V);
    k_raster<<<256 * NSLICE, 256, 0, stream>>>(fd, F, sliceLen, zb);
    k_shade<<<HW / 256, 256, 0, stream>>>(zb, fd, faces, verts, vn, tm, out);
}

// Round 3
// 352.248 us; speedup vs baseline: 4.4774x; 2.1899x over previous
//
#include <hip/hip_runtime.h>
#include <math.h>

#define IMGSZ 256
#define HW (IMGSZ * IMGSZ)
#define EPSF 1e-8f
#define BIGF 1e10f
#define SLICE_LEN 512
#define MARG 1e-4f

// ---------------- Kernel A: vertex transform + zero vn accumulator ----------
__global__ void k_transform(const float* __restrict__ verts,
                            const float* __restrict__ tm,
                            const float* __restrict__ focal,
                            float* __restrict__ xn, float* __restrict__ yn,
                            float* __restrict__ zv, float* __restrict__ vnacc,
                            int V) {
#pragma clang fp contract(off)
    int i = blockIdx.x * blockDim.x + threadIdx.x;
    if (i >= V) return;
    float vx = verts[i * 3 + 0], vy = verts[i * 3 + 1], vz = verts[i * 3 + 2];
    float xv = ((vx * tm[0] + vy * tm[4]) + vz * tm[8]) + tm[3];
    float yv = ((vx * tm[1] + vy * tm[5]) + vz * tm[9]) + tm[7];
    float zw = ((vx * tm[2] + vy * tm[6]) + vz * tm[10]) + tm[11];
    float zc = fmaxf(zw, EPSF);
    float fx = 2.0f * focal[0] / (float)IMGSZ;
    float fy = 2.0f * focal[1] / (float)IMGSZ;
    xn[i] = fx * xv / zc;
    yn[i] = fy * yv / zc;
    zv[i] = zw;
    vnacc[i * 3 + 0] = 0.0f;
    vnacc[i * 3 + 1] = 0.0f;
    vnacc[i * 3 + 2] = 0.0f;
}

// ---------------- Kernel B: per-face setup + normal accumulation ------------
__global__ void k_facesetup(const int* __restrict__ faces,
                            const float* __restrict__ verts,
                            const float* __restrict__ xn,
                            const float* __restrict__ yn,
                            const float* __restrict__ zv,
                            float4* __restrict__ fd,
                            float* __restrict__ vnacc, int F) {
#pragma clang fp contract(off)
    int f = blockIdx.x * blockDim.x + threadIdx.x;
    if (f >= F) return;
    int i0 = faces[f * 3 + 0], i1 = faces[f * 3 + 1], i2 = faces[f * 3 + 2];
    float x0 = xn[i0], x1 = xn[i1], x2 = xn[i2];
    float y0 = yn[i0], y1 = yn[i1], y2 = yn[i2];
    float z0 = zv[i0], z1 = zv[i1], z2 = zv[i2];
    float area = (x1 - x0) * (y2 - y0) - (x2 - x0) * (y1 - y0);
    bool zok = (z0 > EPSF) && (z1 > EPSF) && (z2 > EPSF);
    float areaStore = zok ? area : 0.0f;  // area==0 => culled (|area|<=EPS)
    fd[f * 3 + 0] = make_float4(x0, y0, x1, y1);
    fd[f * 3 + 1] = make_float4(x2, y2, areaStore, __int_as_float(f));
    fd[f * 3 + 2] = make_float4(fmaxf(z0, EPSF), fmaxf(z1, EPSF), fmaxf(z2, EPSF), 0.0f);
    float a0 = verts[i0 * 3 + 0], a1 = verts[i0 * 3 + 1], a2 = verts[i0 * 3 + 2];
    float b0 = verts[i1 * 3 + 0], b1 = verts[i1 * 3 + 1], b2 = verts[i1 * 3 + 2];
    float c0 = verts[i2 * 3 + 0], c1 = verts[i2 * 3 + 1], c2 = verts[i2 * 3 + 2];
    float e1x = b0 - a0, e1y = b1 - a1, e1z = b2 - a2;
    float e2x = c0 - a0, e2y = c1 - a1, e2z = c2 - a2;
    float nx = e1y * e2z - e1z * e2y;
    float ny = e1z * e2x - e1x * e2z;
    float nz = e1x * e2y - e1y * e2x;
    atomicAdd(&vnacc[i0 * 3 + 0], nx);
    atomicAdd(&vnacc[i0 * 3 + 1], ny);
    atomicAdd(&vnacc[i0 * 3 + 2], nz);
    atomicAdd(&vnacc[i1 * 3 + 0], nx);
    atomicAdd(&vnacc[i1 * 3 + 1], ny);
    atomicAdd(&vnacc[i1 * 3 + 2], nz);
    atomicAdd(&vnacc[i2 * 3 + 0], nx);
    atomicAdd(&vnacc[i2 * 3 + 1], ny);
    atomicAdd(&vnacc[i2 * 3 + 2], nz);
}

// ---------------- Kernel C: normalize vertex normals ------------------------
__global__ void k_vnorm(float* __restrict__ vn, int V) {
#pragma clang fp contract(off)
    int i = blockIdx.x * blockDim.x + threadIdx.x;
    if (i >= V) return;
    float x = vn[i * 3 + 0], y = vn[i * 3 + 1], z = vn[i * 3 + 2];
    float n = sqrtf((x * x + y * y) + z * z) + EPSF;
    vn[i * 3 + 0] = x / n;
    vn[i * 3 + 1] = y / n;
    vn[i * 3 + 2] = z / n;
}

// ---------------- Kernel Z: init packed z-buffer ----------------------------
__global__ void k_zinit(unsigned long long* __restrict__ zb) {
    zb[blockIdx.x * 256 + threadIdx.x] = 0xFFFFFFFFFFFFFFFFull;
}

// ---------------- Kernel D: tiled raster (face-sliced, atomic merge) --------
__launch_bounds__(256)
__global__ void k_raster(const float4* __restrict__ fd, int F,
                         unsigned long long* __restrict__ zb) {
#pragma clang fp contract(off)
    __shared__ float4 sfd[256 * 3];
    __shared__ int scnt[4];

    int t = threadIdx.x;
    int lane = t & 63, wid = t >> 6;
    int tile = blockIdx.x & 255;
    int slice = blockIdx.x >> 8;
    int tileX = tile & 15, tileY = tile >> 4;
    int col = tileX * 16 + (t & 15);
    int row = tileY * 16 + (t >> 4);
    float P = 1.0f - 2.0f * ((float)col + 0.5f) / (float)IMGSZ;
    float Q = 1.0f - 2.0f * ((float)row + 0.5f) / (float)IMGSZ;
    // NDC x decreases with col; y decreases with row
    float txmax = 1.0f - 2.0f * ((float)(tileX * 16) + 0.5f) / (float)IMGSZ;
    float txmin = 1.0f - 2.0f * ((float)(tileX * 16 + 15) + 0.5f) / (float)IMGSZ;
    float tymax = 1.0f - 2.0f * ((float)(tileY * 16) + 0.5f) / (float)IMGSZ;
    float tymin = 1.0f - 2.0f * ((float)(tileY * 16 + 15) + 0.5f) / (float)IMGSZ;
    const float M = 1e-4f;

    int fbeg = slice * SLICE_LEN;
    int fend = fbeg + SLICE_LEN;
    if (fend > F) fend = F;

    unsigned long long bestpk = 0xFFFFFFFFFFFFFFFFull;

    for (int base = fbeg; base < fend; base += 256) {
        int f = base + t;
        bool pass = false;
        float4 A, B, C;
        if (f < fend) {
            A = fd[f * 3 + 0];
            B = fd[f * 3 + 1];
            C = fd[f * 3 + 2];
            float area = B.z;
            if (fabsf(area) > EPSF) {
                float x0 = A.x, y0 = A.y, x1 = A.z, y1 = A.w, x2 = B.x, y2 = B.y;
                float mnx = fminf(fminf(x0, x1), x2);
                float mxx = fmaxf(fmaxf(x0, x1), x2);
                float mny = fminf(fminf(y0, y1), y2);
                float mxy = fmaxf(fmaxf(y0, y1), y2);
                pass = (mnx <= txmax + M) && (mxx >= txmin - M) &&
                       (mny <= tymax + M) && (mxy >= tymin - M);
                if (pass) {
                    // conservative exact triangle-vs-tile: edge fns are affine
                    // in (P,Q); extremum over tile rect is at a corner.
                    float a0 = y1 - y2, bb0 = x2 - x1, k0 = x1 * y2 - x2 * y1;
                    float a1 = y2 - y0, bb1 = x0 - x2, k1 = x2 * y0 - x0 * y2;
                    float a2 = y0 - y1, bb2 = x1 - x0, k2 = x0 * y1 - x1 * y0;
                    if (area > 0.0f) {
                        float w0m = k0 + fmaxf(a0 * txmin, a0 * txmax) + fmaxf(bb0 * tymin, bb0 * tymax);
                        float w1m = k1 + fmaxf(a1 * txmin, a1 * txmax) + fmaxf(bb1 * tymin, bb1 * tymax);
                        float w2m = k2 + fmaxf(a2 * txmin, a2 * txmax) + fmaxf(bb2 * tymin, bb2 * tymax);
                        pass = (w0m >= -MARG) && (w1m >= -MARG) && (w2m >= -MARG);
                    } else {
                        float w0m = k0 + fminf(a0 * txmin, a0 * txmax) + fminf(bb0 * tymin, bb0 * tymax);
                        float w1m = k1 + fminf(a1 * txmin, a1 * txmax) + fminf(bb1 * tymin, bb1 * tymax);
                        float w2m = k2 + fminf(a2 * txmin, a2 * txmax) + fminf(bb2 * tymin, bb2 * tymax);
                        pass = (w0m <= MARG) && (w1m <= MARG) && (w2m <= MARG);
                    }
                }
            }
        }
        unsigned long long m = __ballot(pass);
        if (lane == 0) scnt[wid] = __popcll(m);
        __syncthreads();
        int off = 0;
#pragma unroll
        for (int w = 0; w < 4; ++w)
            if (w < wid) off += scnt[w];
        int total = scnt[0] + scnt[1] + scnt[2] + scnt[3];
        if (pass) {
            int rank = __popcll(m & ((1ull << lane) - 1ull));
            int s = off + rank;
            sfd[s * 3 + 0] = A;
            sfd[s * 3 + 1] = B;
            sfd[s * 3 + 2] = C;
        }
        __syncthreads();
        for (int s = 0; s < total; ++s) {
            float4 a = sfd[s * 3 + 0], b = sfd[s * 3 + 1], c = sfd[s * 3 + 2];
            float e0x = a.x - P, e0y = a.y - Q;
            float e1x = a.z - P, e1y = a.w - Q;
            float e2x = b.x - P, e2y = b.y - Q;
            float w0 = e1x * e2y - e2x * e1y;
            float w1 = e2x * e0y - e0x * e2y;
            float area = b.z;
            float w2 = (area - w0) - w1;
            bool inside = (area > 0.0f) ? (w0 >= 0.0f && w1 >= 0.0f && w2 >= 0.0f)
                                        : (w0 <= 0.0f && w1 <= 0.0f && w2 <= 0.0f);
            if (inside) {
                float b0v = w0 / area, b1v = w1 / area, b2v = w2 / area;
                float t0 = b0v / c.x, t1 = b1v / c.y, t2v = b2v / c.z;
                float invz = (t0 + t1) + t2v;
                float zpix = 1.0f / fmaxf(invz, EPSF);
                unsigned long long pk =
                    ((unsigned long long)(unsigned int)__float_as_int(zpix) << 32) |
                    (unsigned int)__float_as_int(b.w);
                if (pk < bestpk) bestpk = pk;
            }
        }
        __syncthreads();
    }

    if (bestpk != 0xFFFFFFFFFFFFFFFFull) {
        int pix = row * IMGSZ + col;
        atomicMin(&zb[pix], bestpk);
    }
}

// ---------------- Kernel E: shade winners -----------------------------------
__launch_bounds__(256)
__global__ void k_shade(const unsigned long long* __restrict__ zb,
                        const float4* __restrict__ fd,
                        const int* __restrict__ faces,
                        const float* __restrict__ verts,
                        const float* __restrict__ vn,
                        const float* __restrict__ tm,
                        float* __restrict__ out) {
#pragma clang fp contract(off)
    int pix = blockIdx.x * 256 + threadIdx.x;
    unsigned long long pk = zb[pix];
    float val = 0.0f, alpha = 0.0f;
    if (pk != 0xFFFFFFFFFFFFFFFFull) {
        int bestf = (int)(unsigned int)(pk & 0xFFFFFFFFull);
        int col = pix & (IMGSZ - 1), row = pix >> 8;
        float P = 1.0f - 2.0f * ((float)col + 0.5f) / (float)IMGSZ;
        float Q = 1.0f - 2.0f * ((float)row + 0.5f) / (float)IMGSZ;
        float4 a = fd[bestf * 3 + 0], b = fd[bestf * 3 + 1], c = fd[bestf * 3 + 2];
        float e0x = a.x - P, e0y = a.y - Q;
        float e1x = a.z - P, e1y = a.w - Q;
        float e2x = b.x - P, e2y = b.y - Q;
        float w0 = e1x * e2y - e2x * e1y;
        float w1 = e2x * e0y - e0x * e2y;
        float area = b.z;
        float t0 = (w0 / area) / c.x, t1 = (w1 / area) / c.y;
        float t2v = (((area - w0) - w1) / area) / c.z;
        float invz = (t0 + t1) + t2v;
        float zpix = 1.0f / fmaxf(invz, EPSF);
        float bp0 = t0 * zpix, bp1 = t1 * zpix;

        int i0 = faces[bestf * 3 + 0], i1 = faces[bestf * 3 + 1], i2 = faces[bestf * 3 + 2];
        float b0v = bp0, b1v = bp1, b2v = (1.0f - bp0) - bp1;
        float Pwx = (b0v * verts[i0 * 3 + 0] + b1v * verts[i1 * 3 + 0]) + b2v * verts[i2 * 3 + 0];
        float Pwy = (b0v * verts[i0 * 3 + 1] + b1v * verts[i1 * 3 + 1]) + b2v * verts[i2 * 3 + 1];
        float Pwz = (b0v * verts[i0 * 3 + 2] + b1v * verts[i1 * 3 + 2]) + b2v * verts[i2 * 3 + 2];
        float Nx = (b0v * vn[i0 * 3 + 0] + b1v * vn[i1 * 3 + 0]) + b2v * vn[i2 * 3 + 0];
        float Ny = (b0v * vn[i0 * 3 + 1] + b1v * vn[i1 * 3 + 1]) + b2v * vn[i2 * 3 + 1];
        float Nz = (b0v * vn[i0 * 3 + 2] + b1v * vn[i1 * 3 + 2]) + b2v * vn[i2 * 3 + 2];
        float nn = sqrtf((Nx * Nx + Ny * Ny) + Nz * Nz) + EPSF;
        Nx /= nn; Ny /= nn; Nz /= nn;
        float T0 = tm[3], T1 = tm[7], T2 = tm[11];
        float camx = -((T0 * tm[0] + T1 * tm[1]) + T2 * tm[2]);
        float camy = -((T0 * tm[4] + T1 * tm[5]) + T2 * tm[6]);
        float camz = -((T0 * tm[8] + T1 * tm[9]) + T2 * tm[10]);
        float Ldx = 0.0f - Pwx, Ldy = 0.0f - Pwy, Ldz = 3.0f - Pwz;
        float ln = sqrtf((Ldx * Ldx + Ldy * Ldy) + Ldz * Ldz) + EPSF;
        Ldx /= ln; Ldy /= ln; Ldz /= ln;
        float Vx = camx - Pwx, Vy = camy - Pwy, Vz = camz - Pwz;
        float vv = sqrtf((Vx * Vx + Vy * Vy) + Vz * Vz) + EPSF;
        Vx /= vv; Vy /= vv; Vz /= vv;
        float dt = (Nx * Ldx + Ny * Ldy) + Nz * Ldz;
        float ndl = fmaxf(dt, 0.0f);
        float twodt = 2.0f * dt;
        float rx = -Ldx + twodt * Nx;
        float ry = -Ldy + twodt * Ny;
        float rz = -Ldz + twodt * Nz;
        float sdot = (rx * Vx + ry * Vy) + rz * Vz;
        float sb = fmaxf(sdot, 0.0f);
        float s2 = sb * sb, s4 = s2 * s2, s8 = s4 * s4, s16 = s8 * s8, s32 = s16 * s16;
        float spec = s32 * s32;  // sb^64
        float shade = (0.5f + 0.3f * ndl) + 0.2f * spec;
        val = shade * 255.0f;
        alpha = 1.0f;
    }
    out[0 * HW + pix] = val;
    out[1 * HW + pix] = val;
    out[2 * HW + pix] = val;
    out[3 * HW + pix] = alpha;
}

// ---------------- launcher --------------------------------------------------
extern "C" void kernel_launch(void* const* d_in, const int* in_sizes, int n_in,
                              void* d_out, int out_size, void* d_ws, size_t ws_size,
                              hipStream_t stream) {
    const float* verts = (const float*)d_in[0];
    const float* tm = (const float*)d_in[1];
    const float* focal = (const float*)d_in[2];
    const int* faces = (const int*)d_in[3];
    int V = in_sizes[0] / 3;  // B=1
    int F = in_sizes[3] / 3;

    unsigned long long* zb = (unsigned long long*)d_ws;
    float* ws = (float*)d_ws + 2 * (size_t)HW;
    float* xn = ws;
    float* yn = ws + V;
    float* zv = ws + 2 * (size_t)V;
    float* vn = ws + 3 * (size_t)V;
    size_t fdOff = (6 * (size_t)V + 3) & ~(size_t)3;  // 16B-align
    float4* fd = (float4*)(ws + fdOff);
    float* out = (float*)d_out;

    int vb = (V + 255) / 256;
    int fb = (F + 255) / 256;
    int nslice = (F + SLICE_LEN - 1) / SLICE_LEN;
    k_transform<<<vb, 256, 0, stream>>>(verts, tm, focal, xn, yn, zv, vn, V);
    k_zinit<<<HW / 256, 256, 0, stream>>>(zb);
    k_facesetup<<<fb, 256, 0, stream>>>(faces, verts, xn, yn, zv, fd, vn, F);
    k_vnorm<<<vb, 256, 0, stream>>>(vn, V);
    k_raster<<<256 * nslice, 256, 0, stream>>>(fd, F, zb);
    k_shade<<<HW / 256, 256, 0, stream>>>(zb, fd, faces, verts, vn, tm, out);
}

// Round 4
// 248.104 us; speedup vs baseline: 6.3569x; 1.4198x over previous
//
#include <hip/hip_runtime.h>
#include <math.h>

#define IMGSZ 256
#define HW (IMGSZ * IMGSZ)
#define EPSF 1e-8f
#define BIGF 1e10f
#define SLICE_LEN 1024
#define MARG 1e-4f
// sentinel: depth = BIGF (0x501502F9), fid = ~0
#define SENTINEL 0x501502F9FFFFFFFFull

// ---------------- Kernel A: vertex transform + zero vn accumulator ----------
__global__ void k_transform(const float* __restrict__ verts,
                            const float* __restrict__ tm,
                            const float* __restrict__ focal,
                            float* __restrict__ xn, float* __restrict__ yn,
                            float* __restrict__ zv, float* __restrict__ vnacc,
                            int V) {
#pragma clang fp contract(off)
    int i = blockIdx.x * blockDim.x + threadIdx.x;
    if (i >= V) return;
    float vx = verts[i * 3 + 0], vy = verts[i * 3 + 1], vz = verts[i * 3 + 2];
    float xv = ((vx * tm[0] + vy * tm[4]) + vz * tm[8]) + tm[3];
    float yv = ((vx * tm[1] + vy * tm[5]) + vz * tm[9]) + tm[7];
    float zw = ((vx * tm[2] + vy * tm[6]) + vz * tm[10]) + tm[11];
    float zc = fmaxf(zw, EPSF);
    float fx = 2.0f * focal[0] / (float)IMGSZ;
    float fy = 2.0f * focal[1] / (float)IMGSZ;
    xn[i] = fx * xv / zc;
    yn[i] = fy * yv / zc;
    zv[i] = zw;
    vnacc[i * 3 + 0] = 0.0f;
    vnacc[i * 3 + 1] = 0.0f;
    vnacc[i * 3 + 2] = 0.0f;
}

// ---------------- Kernel B: per-face setup + normal accumulation ------------
__global__ void k_facesetup(const int* __restrict__ faces,
                            const float* __restrict__ verts,
                            const float* __restrict__ xn,
                            const float* __restrict__ yn,
                            const float* __restrict__ zv,
                            float4* __restrict__ fd,
                            float* __restrict__ vnacc, int F) {
#pragma clang fp contract(off)
    int f = blockIdx.x * blockDim.x + threadIdx.x;
    if (f >= F) return;
    int i0 = faces[f * 3 + 0], i1 = faces[f * 3 + 1], i2 = faces[f * 3 + 2];
    float x0 = xn[i0], x1 = xn[i1], x2 = xn[i2];
    float y0 = yn[i0], y1 = yn[i1], y2 = yn[i2];
    float z0 = zv[i0], z1 = zv[i1], z2 = zv[i2];
    float area = (x1 - x0) * (y2 - y0) - (x2 - x0) * (y1 - y0);
    bool zok = (z0 > EPSF) && (z1 > EPSF) && (z2 > EPSF);
    float areaStore = zok ? area : 0.0f;  // area==0 => culled (|area|<=EPS)
    float z0c = fmaxf(z0, EPSF), z1c = fmaxf(z1, EPSF), z2c = fmaxf(z2, EPSF);
    // conservative lower bound of interpolated zpix (harmonic interp keeps
    // zpix within [zmin,zmax] up to few-ulp rounding; 1e-5 margin covers it)
    float zminb = fminf(fminf(z0c, z1c), z2c) * (1.0f - 1e-5f);
    fd[f * 3 + 0] = make_float4(x0, y0, x1, y1);
    fd[f * 3 + 1] = make_float4(x2, y2, areaStore, __int_as_float(f));
    fd[f * 3 + 2] = make_float4(z0c, z1c, z2c, zminb);
    float a0 = verts[i0 * 3 + 0], a1 = verts[i0 * 3 + 1], a2 = verts[i0 * 3 + 2];
    float b0 = verts[i1 * 3 + 0], b1 = verts[i1 * 3 + 1], b2 = verts[i1 * 3 + 2];
    float c0 = verts[i2 * 3 + 0], c1 = verts[i2 * 3 + 1], c2 = verts[i2 * 3 + 2];
    float e1x = b0 - a0, e1y = b1 - a1, e1z = b2 - a2;
    float e2x = c0 - a0, e2y = c1 - a1, e2z = c2 - a2;
    float nx = e1y * e2z - e1z * e2y;
    float ny = e1z * e2x - e1x * e2z;
    float nz = e1x * e2y - e1y * e2x;
    atomicAdd(&vnacc[i0 * 3 + 0], nx);
    atomicAdd(&vnacc[i0 * 3 + 1], ny);
    atomicAdd(&vnacc[i0 * 3 + 2], nz);
    atomicAdd(&vnacc[i1 * 3 + 0], nx);
    atomicAdd(&vnacc[i1 * 3 + 1], ny);
    atomicAdd(&vnacc[i1 * 3 + 2], nz);
    atomicAdd(&vnacc[i2 * 3 + 0], nx);
    atomicAdd(&vnacc[i2 * 3 + 1], ny);
    atomicAdd(&vnacc[i2 * 3 + 2], nz);
}

// ---------------- Kernel C: normalize vertex normals ------------------------
__global__ void k_vnorm(float* __restrict__ vn, int V) {
#pragma clang fp contract(off)
    int i = blockIdx.x * blockDim.x + threadIdx.x;
    if (i >= V) return;
    float x = vn[i * 3 + 0], y = vn[i * 3 + 1], z = vn[i * 3 + 2];
    float n = sqrtf((x * x + y * y) + z * z) + EPSF;
    vn[i * 3 + 0] = x / n;
    vn[i * 3 + 1] = y / n;
    vn[i * 3 + 2] = z / n;
}

// ---------------- Kernel Z: init packed z-buffer ----------------------------
__global__ void k_zinit(unsigned long long* __restrict__ zb) {
    zb[blockIdx.x * 256 + threadIdx.x] = SENTINEL;
}

// ---------------- Kernel D: tiled raster (face-sliced, atomic merge) --------
__launch_bounds__(256)
__global__ void k_raster(const float4* __restrict__ fd, int F,
                         unsigned long long* __restrict__ zb) {
#pragma clang fp contract(off)
    __shared__ float4 sfd[256 * 3];
    __shared__ int scnt[4];

    int t = threadIdx.x;
    int lane = t & 63, wid = t >> 6;
    int tile = blockIdx.x & 255;
    int slice = blockIdx.x >> 8;
    int tileX = tile & 15, tileY = tile >> 4;
    int col = tileX * 16 + (t & 15);
    int row = tileY * 16 + (t >> 4);
    int pix = row * IMGSZ + col;
    float P = 1.0f - 2.0f * ((float)col + 0.5f) / (float)IMGSZ;
    float Q = 1.0f - 2.0f * ((float)row + 0.5f) / (float)IMGSZ;
    // NDC x decreases with col; y decreases with row
    float txmax = 1.0f - 2.0f * ((float)(tileX * 16) + 0.5f) / (float)IMGSZ;
    float txmin = 1.0f - 2.0f * ((float)(tileX * 16 + 15) + 0.5f) / (float)IMGSZ;
    float tymax = 1.0f - 2.0f * ((float)(tileY * 16) + 0.5f) / (float)IMGSZ;
    float tymin = 1.0f - 2.0f * ((float)(tileY * 16 + 15) + 0.5f) / (float)IMGSZ;
    const float M = 1e-4f;

    int fbeg = slice * SLICE_LEN;
    int fend = fbeg + SLICE_LEN;
    if (fend > F) fend = F;

    unsigned long long bestpk = SENTINEL;
    float bestz = BIGF;

    for (int base = fbeg; base < fend; base += 256) {
        // merge in other blocks' published progress (deterministic: final
        // result is the global lexicographic min regardless of timing)
        unsigned long long ext = zb[pix];
        if (ext < bestpk) {
            bestpk = ext;
            bestz = __uint_as_float((unsigned int)(ext >> 32));
        }
        int f = base + t;
        bool pass = false;
        float4 A, B, C;
        if (f < fend) {
            A = fd[f * 3 + 0];
            B = fd[f * 3 + 1];
            C = fd[f * 3 + 2];
            float area = B.z;
            if (fabsf(area) > EPSF) {
                float x0 = A.x, y0 = A.y, x1 = A.z, y1 = A.w, x2 = B.x, y2 = B.y;
                float mnx = fminf(fminf(x0, x1), x2);
                float mxx = fmaxf(fmaxf(x0, x1), x2);
                float mny = fminf(fminf(y0, y1), y2);
                float mxy = fmaxf(fmaxf(y0, y1), y2);
                pass = (mnx <= txmax + M) && (mxx >= txmin - M) &&
                       (mny <= tymax + M) && (mxy >= tymin - M);
                if (pass) {
                    // conservative exact triangle-vs-tile: edge fns affine in
                    // (P,Q); extremum over the tile rect is at a corner.
                    float a0 = y1 - y2, bb0 = x2 - x1, k0 = x1 * y2 - x2 * y1;
                    float a1 = y2 - y0, bb1 = x0 - x2, k1 = x2 * y0 - x0 * y2;
                    float a2 = y0 - y1, bb2 = x1 - x0, k2 = x0 * y1 - x1 * y0;
                    if (area > 0.0f) {
                        float w0m = k0 + fmaxf(a0 * txmin, a0 * txmax) + fmaxf(bb0 * tymin, bb0 * tymax);
                        float w1m = k1 + fmaxf(a1 * txmin, a1 * txmax) + fmaxf(bb1 * tymin, bb1 * tymax);
                        float w2m = k2 + fmaxf(a2 * txmin, a2 * txmax) + fmaxf(bb2 * tymin, bb2 * tymax);
                        pass = (w0m >= -MARG) && (w1m >= -MARG) && (w2m >= -MARG);
                    } else {
                        float w0m = k0 + fminf(a0 * txmin, a0 * txmax) + fminf(bb0 * tymin, bb0 * tymax);
                        float w1m = k1 + fminf(a1 * txmin, a1 * txmax) + fminf(bb1 * tymin, bb1 * tymax);
                        float w2m = k2 + fminf(a2 * txmin, a2 * txmax) + fminf(bb2 * tymin, bb2 * tymax);
                        pass = (w0m <= MARG) && (w1m <= MARG) && (w2m <= MARG);
                    }
                }
            }
        }
        unsigned long long m = __ballot(pass);
        if (lane == 0) scnt[wid] = __popcll(m);
        __syncthreads();
        int off = 0;
#pragma unroll
        for (int w = 0; w < 4; ++w)
            if (w < wid) off += scnt[w];
        int total = scnt[0] + scnt[1] + scnt[2] + scnt[3];
        if (pass) {
            int rank = __popcll(m & ((1ull << lane) - 1ull));
            int s = off + rank;  // order-preserving compaction
            sfd[s * 3 + 0] = A;
            sfd[s * 3 + 1] = B;
            sfd[s * 3 + 2] = C;
        }
        __syncthreads();
        for (int s = 0; s < total; ++s) {
            float4 a = sfd[s * 3 + 0], b = sfd[s * 3 + 1], c = sfd[s * 3 + 2];
            float e0x = a.x - P, e0y = a.y - Q;
            float e1x = a.z - P, e1y = a.w - Q;
            float e2x = b.x - P, e2y = b.y - Q;
            float w0 = e1x * e2y - e2x * e1y;
            float w1 = e2x * e0y - e0x * e2y;
            float area = b.z;
            float w2 = (area - w0) - w1;
            bool inside = (area > 0.0f) ? (w0 >= 0.0f && w1 >= 0.0f && w2 >= 0.0f)
                                        : (w0 <= 0.0f && w1 <= 0.0f && w2 <= 0.0f);
            // z-reject: zpix >= c.w (conservative); within a block fid is
            // strictly increasing, so depth-ties can never improve pk either.
            bool want = inside && (c.w < bestz);
            if (__any(want)) {
                if (want) {
                    float b0v = w0 / area, b1v = w1 / area, b2v = w2 / area;
                    float t0 = b0v / c.x, t1 = b1v / c.y, t2v = b2v / c.z;
                    float invz = (t0 + t1) + t2v;
                    float zpix = 1.0f / fmaxf(invz, EPSF);
                    unsigned long long pk =
                        ((unsigned long long)(unsigned int)__float_as_int(zpix) << 32) |
                        (unsigned int)__float_as_int(b.w);
                    if (pk < bestpk) {
                        bestpk = pk;
                        bestz = zpix;
                    }
                }
            }
        }
        // publish progress so concurrent blocks can z-reject against it
        if (bestpk < ext) atomicMin(&zb[pix], bestpk);
        __syncthreads();
    }
}

// ---------------- Kernel E: shade winners -----------------------------------
__launch_bounds__(256)
__global__ void k_shade(const unsigned long long* __restrict__ zb,
                        const float4* __restrict__ fd,
                        const int* __restrict__ faces,
                        const float* __restrict__ verts,
                        const float* __restrict__ vn,
                        const float* __restrict__ tm,
                        float* __restrict__ out) {
#pragma clang fp contract(off)
    int pix = blockIdx.x * 256 + threadIdx.x;
    unsigned long long pk = zb[pix];
    float depth = __uint_as_float((unsigned int)(pk >> 32));
    float val = 0.0f, alpha = 0.0f;
    if (depth < 0.5f * BIGF) {
        int bestf = (int)(unsigned int)(pk & 0xFFFFFFFFull);
        int col = pix & (IMGSZ - 1), row = pix >> 8;
        float P = 1.0f - 2.0f * ((float)col + 0.5f) / (float)IMGSZ;
        float Q = 1.0f - 2.0f * ((float)row + 0.5f) / (float)IMGSZ;
        float4 a = fd[bestf * 3 + 0], b = fd[bestf * 3 + 1], c = fd[bestf * 3 + 2];
        float e0x = a.x - P, e0y = a.y - Q;
        float e1x = a.z - P, e1y = a.w - Q;
        float e2x = b.x - P, e2y = b.y - Q;
        float w0 = e1x * e2y - e2x * e1y;
        float w1 = e2x * e0y - e0x * e2y;
        float area = b.z;
        float t0 = (w0 / area) / c.x, t1 = (w1 / area) / c.y;
        float t2v = (((area - w0) - w1) / area) / c.z;
        float invz = (t0 + t1) + t2v;
        float zpix = 1.0f / fmaxf(invz, EPSF);
        float bp0 = t0 * zpix, bp1 = t1 * zpix;

        int i0 = faces[bestf * 3 + 0], i1 = faces[bestf * 3 + 1], i2 = faces[bestf * 3 + 2];
        float b0v = bp0, b1v = bp1, b2v = (1.0f - bp0) - bp1;
        float Pwx = (b0v * verts[i0 * 3 + 0] + b1v * verts[i1 * 3 + 0]) + b2v * verts[i2 * 3 + 0];
        float Pwy = (b0v * verts[i0 * 3 + 1] + b1v * verts[i1 * 3 + 1]) + b2v * verts[i2 * 3 + 1];
        float Pwz = (b0v * verts[i0 * 3 + 2] + b1v * verts[i1 * 3 + 2]) + b2v * verts[i2 * 3 + 2];
        float Nx = (b0v * vn[i0 * 3 + 0] + b1v * vn[i1 * 3 + 0]) + b2v * vn[i2 * 3 + 0];
        float Ny = (b0v * vn[i0 * 3 + 1] + b1v * vn[i1 * 3 + 1]) + b2v * vn[i2 * 3 + 1];
        float Nz = (b0v * vn[i0 * 3 + 2] + b1v * vn[i1 * 3 + 2]) + b2v * vn[i2 * 3 + 2];
        float nn = sqrtf((Nx * Nx + Ny * Ny) + Nz * Nz) + EPSF;
        Nx /= nn; Ny /= nn; Nz /= nn;
        float T0 = tm[3], T1 = tm[7], T2 = tm[11];
        float camx = -((T0 * tm[0] + T1 * tm[1]) + T2 * tm[2]);
        float camy = -((T0 * tm[4] + T1 * tm[5]) + T2 * tm[6]);
        float camz = -((T0 * tm[8] + T1 * tm[9]) + T2 * tm[10]);
        float Ldx = 0.0f - Pwx, Ldy = 0.0f - Pwy, Ldz = 3.0f - Pwz;
        float ln = sqrtf((Ldx * Ldx + Ldy * Ldy) + Ldz * Ldz) + EPSF;
        Ldx /= ln; Ldy /= ln; Ldz /= ln;
        float Vx = camx - Pwx, Vy = camy - Pwy, Vz = camz - Pwz;
        float vv = sqrtf((Vx * Vx + Vy * Vy) + Vz * Vz) + EPSF;
        Vx /= vv; Vy /= vv; Vz /= vv;
        float dt = (Nx * Ldx + Ny * Ldy) + Nz * Ldz;
        float ndl = fmaxf(dt, 0.0f);
        float twodt = 2.0f * dt;
        float rx = -Ldx + twodt * Nx;
        float ry = -Ldy + twodt * Ny;
        float rz = -Ldz + twodt * Nz;
        float sdot = (rx * Vx + ry * Vy) + rz * Vz;
        float sb = fmaxf(sdot, 0.0f);
        float s2 = sb * sb, s4 = s2 * s2, s8 = s4 * s4, s16 = s8 * s8, s32 = s16 * s16;
        float spec = s32 * s32;  // sb^64
        float shade = (0.5f + 0.3f * ndl) + 0.2f * spec;
        val = shade * 255.0f;
        alpha = 1.0f;
    }
    out[0 * HW + pix] = val;
    out[1 * HW + pix] = val;
    out[2 * HW + pix] = val;
    out[3 * HW + pix] = alpha;
}

// ---------------- launcher --------------------------------------------------
extern "C" void kernel_launch(void* const* d_in, const int* in_sizes, int n_in,
                              void* d_out, int out_size, void* d_ws, size_t ws_size,
                              hipStream_t stream) {
    const float* verts = (const float*)d_in[0];
    const float* tm = (const float*)d_in[1];
    const float* focal = (const float*)d_in[2];
    const int* faces = (const int*)d_in[3];
    int V = in_sizes[0] / 3;  // B=1
    int F = in_sizes[3] / 3;

    unsigned long long* zb = (unsigned long long*)d_ws;
    float* ws = (float*)d_ws + 2 * (size_t)HW;
    float* xn = ws;
    float* yn = ws + V;
    float* zv = ws + 2 * (size_t)V;
    float* vn = ws + 3 * (size_t)V;
    size_t fdOff = (6 * (size_t)V + 3) & ~(size_t)3;  // 16B-align
    float4* fd = (float4*)(ws + fdOff);
    float* out = (float*)d_out;

    int vb = (V + 255) / 256;
    int fb = (F + 255) / 256;
    int nslice = (F + SLICE_LEN - 1) / SLICE_LEN;
    k_transform<<<vb, 256, 0, stream>>>(verts, tm, focal, xn, yn, zv, vn, V);
    k_zinit<<<HW / 256, 256, 0, stream>>>(zb);
    k_facesetup<<<fb, 256, 0, stream>>>(faces, verts, xn, yn, zv, fd, vn, F);
    k_vnorm<<<vb, 256, 0, stream>>>(vn, V);
    k_raster<<<256 * nslice, 256, 0, stream>>>(fd, F, zb);
    k_shade<<<HW / 256, 256, 0, stream>>>(zb, fd, faces, verts, vn, tm, out);
}